// Round 10
// baseline (736.579 us; speedup 1.0000x reference)
//
#include <hip/hip_runtime.h>

// DiffeqSolver: 49 RK4(3/8) steps of y' = W2 @ tanh(W1 @ y + b1) + b2
// 6144 rows, dim 128 (123+5 aug), hidden 256. Output (3,2048,50,128) fp32.
//
// Round 11b: two co-resident blocks per CU — fill the latency chain.
//  (11a was an infra container failure; kernel audited — barrier counts 785/785
//   matched, WAR hazards barrier-separated, occupancy plan intact — resubmit.)
//  - Eliminated by measurement: MFMA throughput (52% busy), LDS throughput
//    (halved in R10 -> -3%), VALU throughput (diet in R9 -> -2%), sync
//    topology (3 nulls). The ~3400 cy/period invariant is a serial LATENCY
//    chain (barrier -> ds_read lat -> MFMA dep-chain -> tanh/split tail ->
//    publish -> barrier drain) x 392 periods, all waves in lockstep.
//  - Latency-bound loops need co-resident independent work. R10's fat-wave
//    layout compiles to VGPR_Count=128 -> 4 waves/SIMD schedulable (pool
//    512/SIMD) -> TWO 8-wave blocks per CU.
//  - Grid 512 x 12 rows, ONE group per block, strict A/B period alternation:
//    period 2e: A-waves (4x4 W1 h-tiles) compute H_e = tanh(W1 Y_e + b1);
//    period 2e+1: B-waves (4x2 W2 d-tiles) compute K_e = W2 H_e + b2, fold
//    RK4(3/8) state, publish Y_{e+1}. 48 MFMA/SIMD/period per block; two
//    blocks -> 96/SIMD/period (same pipe demand as R10) with two
//    INDEPENDENT latency chains interleaving per SIMD.
//  - Single-buffered yf/hf: A reads yf in 2e, B rewrites it in 2e+1 (WAR
//    separated by barrier); B reads hf in 2e+1, A rewrites in 2e+2. ~25 KB.
//  - Wave-level code = R10 verbatim minus the group dimension: frag-linear
//    conflict-free LDS, cvt_pkrtz packed publishes, kt=0 peel, static-e RK
//    bodies, exp2 tanh, split x = hi(f16) + 2^-11 lo(f16), 3 MFMA products.

typedef _Float16 half8  __attribute__((ext_vector_type(8)));
typedef __fp16   fp16x2 __attribute__((ext_vector_type(2)));   // cvt_pkrtz result
typedef float    floatx4 __attribute__((ext_vector_type(4)));
typedef unsigned int uint2v __attribute__((ext_vector_type(2)));

#define NBLK 512
#define DIM  128
#define HID  256
#define ROWS 12           // rows per block (one 16-row MFMA tile, 12 valid)
#define LOSCALE 2048.0f
#define LOINV   (1.0f/2048.0f)
#define K_TANH  2.8853900817779268f   // 2*log2(e)

__device__ __forceinline__ float fast_tanh(float x) {
    float e = __builtin_amdgcn_exp2f(K_TANH * x);
    return 1.0f - 2.0f * __builtin_amdgcn_rcpf(e + 1.0f);
}

struct h2c { _Float16 hi, lo; };
__device__ __forceinline__ h2c split16(float v) {   // RTN; weights init only
    h2c r;
    r.hi = (_Float16)v;
    r.lo = (_Float16)((v - (float)r.hi) * LOSCALE);
    return r;
}

// packed split of 4 f32 -> (hi 4xf16, lo 4xf16) as uint2 each
__device__ __forceinline__ void split4_pk(floatx4 v, uint2v &hi, uint2v &lo) {
    fp16x2 h01 = __builtin_amdgcn_cvt_pkrtz(v[0], v[1]);
    fp16x2 h23 = __builtin_amdgcn_cvt_pkrtz(v[2], v[3]);
    float r0 = (v[0] - (float)h01[0]) * LOSCALE;
    float r1 = (v[1] - (float)h01[1]) * LOSCALE;
    float r2 = (v[2] - (float)h23[0]) * LOSCALE;
    float r3 = (v[3] - (float)h23[1]) * LOSCALE;
    fp16x2 l01 = __builtin_amdgcn_cvt_pkrtz(r0, r1);
    fp16x2 l23 = __builtin_amdgcn_cvt_pkrtz(r2, r3);
    hi[0] = __builtin_bit_cast(unsigned int, h01);
    hi[1] = __builtin_bit_cast(unsigned int, h23);
    lo[0] = __builtin_bit_cast(unsigned int, l01);
    lo[1] = __builtin_bit_cast(unsigned int, l23);
}

__global__ __launch_bounds__(512, 2)
void ode_co_kernel(const float* __restrict__ fp,      // (3,2048,123)
                   const float* __restrict__ tsteps,  // (50)
                   const float* __restrict__ W1,      // (256,128)
                   const float* __restrict__ b1,      // (256)
                   const float* __restrict__ W2,      // (128,256)
                   const float* __restrict__ b2,      // (128)
                   float* __restrict__ out)           // (3,2048,50,128)
{
    // frag-linear: element (batch n, k) at (k>>5)*512 + ((k>>3)&3)*128 + n*8 + (k&7)
    __shared__ __align__(16) _Float16 yfh[2048], yfl[2048];  // k=d  (128)
    __shared__ __align__(16) _Float16 hfh[4096], hfl[4096];  // k=h  (256)
    __shared__ float ts_l[64];

    const int tid  = threadIdx.x;
    const int wave = tid >> 6;
    const int lane = tid & 63;
    const int n16  = lane & 15;
    const int quad = lane >> 4;
    const int hq   = quad >> 1;
    const int blk  = blockIdx.x;

    if (tid < 50) ts_l[tid] = tsteps[tid];

    const floatx4 Z = (floatx4){0.f, 0.f, 0.f, 0.f};

    if (wave < 4) {
        // ======= producer A: H^T = tanh(W1 . Y^T + b1), 4 tiles/wave =======
        const int a = wave;                    // h-rows [64a, 64a+64)
        half8 w1h[4][4], w1l[4][4];            // [i][kt]
        floatx4 bias1[4];
#pragma unroll
        for (int i = 0; i < 4; ++i) {
            bias1[i] = *(const floatx4*)(b1 + 64*a + 16*i + 4*quad);
#pragma unroll
            for (int kt = 0; kt < 4; ++kt) {
                const float* p = W1 + (64*a + 16*i + n16)*DIM + kt*32 + quad*8;
#pragma unroll
                for (int j = 0; j < 8; ++j) {
                    h2c sp = split16(p[j]);
                    w1h[i][kt][j] = sp.hi;
                    w1l[i][kt][j] = sp.lo;
                }
            }
        }
        const int yrd = quad*128 + n16*8;                // + kt*512
        const int hwr = 2*a*512 + n16*8 + 4*(quad&1);    // + (i>>1)*512 + ((2i+hq)&3)*128

        auto a_work = [&]() {
            floatx4 aM[4], aC[4], aD[4];
            {   // kt = 0 peeled: bias / zero as C operand
                half8 ybh = *(const half8*)&yfh[yrd];
                half8 ybl = *(const half8*)&yfl[yrd];
#pragma unroll
                for (int i = 0; i < 4; ++i) {
                    aM[i] = __builtin_amdgcn_mfma_f32_16x16x32_f16(w1h[i][0], ybh, bias1[i], 0,0,0);
                    aC[i] = __builtin_amdgcn_mfma_f32_16x16x32_f16(w1l[i][0], ybh, Z, 0,0,0);
                    aD[i] = __builtin_amdgcn_mfma_f32_16x16x32_f16(w1h[i][0], ybl, Z, 0,0,0);
                }
            }
#pragma unroll
            for (int kt = 1; kt < 4; ++kt) {
                half8 ybh = *(const half8*)&yfh[kt*512 + yrd];
                half8 ybl = *(const half8*)&yfl[kt*512 + yrd];
#pragma unroll
                for (int i = 0; i < 4; ++i) {
                    aM[i] = __builtin_amdgcn_mfma_f32_16x16x32_f16(w1h[i][kt], ybh, aM[i], 0,0,0);
                    aC[i] = __builtin_amdgcn_mfma_f32_16x16x32_f16(w1l[i][kt], ybh, aC[i], 0,0,0);
                    aD[i] = __builtin_amdgcn_mfma_f32_16x16x32_f16(w1h[i][kt], ybl, aD[i], 0,0,0);
                }
            }
#pragma unroll
            for (int i = 0; i < 4; ++i) {
                floatx4 t;
#pragma unroll
                for (int r = 0; r < 4; ++r) {
                    const float v = aM[i][r] + LOINV*(aC[i][r] + aD[i][r]);
                    t[r] = fast_tanh(v);
                }
                uint2v hi, lo;
                split4_pk(t, hi, lo);
                const int off = hwr + (i>>1)*512 + ((2*i + hq) & 3)*128;
                *(uint2v*)&hfh[off] = hi;
                *(uint2v*)&hfl[off] = lo;
            }
        };

        __syncthreads();                       // init: yf_0 published
#pragma unroll 1
        for (int s = 0; s < 49; ++s) {
#pragma unroll 1
            for (int q = 0; q < 4; ++q) {
                a_work();                      // period 2e: H_e
                __syncthreads();               // hf_e ready
                __syncthreads();               // B period done, yf_{e+1} ready
            }
        }
    } else {
        // == consumer B: K^T = W2 . H^T + b2 ; RK fold ; publish, 2 tiles ===
        const int wb = wave - 4;               // d-rows [32wb, 32wb+32)
        half8 w2h[2][8], w2l[2][8];            // [j][kt]
        floatx4 bias2[2];
#pragma unroll
        for (int j = 0; j < 2; ++j) {
            bias2[j] = *(const floatx4*)(b2 + 32*wb + 16*j + 4*quad);
#pragma unroll
            for (int kt = 0; kt < 8; ++kt) {
                const float* p = W2 + (32*wb + 16*j + n16)*HID + kt*32 + quad*8;
#pragma unroll
                for (int jj = 0; jj < 8; ++jj) {
                    h2c sp = split16(p[jj]);
                    w2h[j][kt][jj] = sp.hi;
                    w2l[j][kt][jj] = sp.lo;
                }
            }
        }
        // per-lane state: tile j holds d = 32wb + 16j + 4quad + r, row n16
        floatx4 yg[2] = {Z, Z}, r1[2] = {Z, Z}, uu[2] = {Z, Z};
        if (n16 < ROWS) {
#pragma unroll
            for (int j = 0; j < 2; ++j) {
                const int dj = 32*wb + 16*j + 4*quad;
#pragma unroll
                for (int r = 0; r < 4; ++r) {
                    const int d = dj + r;
                    if (d < 123) yg[j][r] = fp[(blk*ROWS + n16)*123 + d];
                }
            }
            // t = 0 output
            float* p0 = out + ((size_t)(blk*ROWS + n16)*50)*DIM + 32*wb + 4*quad;
            *(floatx4*)&p0[0]  = yg[0];
            *(floatx4*)&p0[16] = yg[1];
        }

        // publish offset, tile j: k = 32wb + 16j + 4quad + r
        const int ywr = wb*512 + n16*8 + 4*(quad&1);     // + ((2j+hq)&3)*128
        auto publish = [&](const floatx4* p) {
#pragma unroll
            for (int j = 0; j < 2; ++j) {
                uint2v hi, lo;
                split4_pk(p[j], hi, lo);
                const int off = ywr + ((2*j + hq) & 3)*128;
                *(uint2v*)&yfh[off] = hi;
                *(uint2v*)&yfl[off] = lo;
            }
        };
        publish(yg);                           // yf_0 = y0

        const int hrd = quad*128 + n16*8;                // + kt*512
        auto b_mm = [&](floatx4* kv) {
            floatx4 bM[2], bC[2], bD[2];
            {   // kt = 0 peeled
                half8 hbh = *(const half8*)&hfh[hrd];
                half8 hbl = *(const half8*)&hfl[hrd];
#pragma unroll
                for (int j = 0; j < 2; ++j) {
                    bM[j] = __builtin_amdgcn_mfma_f32_16x16x32_f16(w2h[j][0], hbh, bias2[j], 0,0,0);
                    bC[j] = __builtin_amdgcn_mfma_f32_16x16x32_f16(w2l[j][0], hbh, Z, 0,0,0);
                    bD[j] = __builtin_amdgcn_mfma_f32_16x16x32_f16(w2h[j][0], hbl, Z, 0,0,0);
                }
            }
#pragma unroll
            for (int kt = 1; kt < 8; ++kt) {
                half8 hbh = *(const half8*)&hfh[kt*512 + hrd];
                half8 hbl = *(const half8*)&hfl[kt*512 + hrd];
#pragma unroll
                for (int j = 0; j < 2; ++j) {
                    bM[j] = __builtin_amdgcn_mfma_f32_16x16x32_f16(w2h[j][kt], hbh, bM[j], 0,0,0);
                    bC[j] = __builtin_amdgcn_mfma_f32_16x16x32_f16(w2l[j][kt], hbh, bC[j], 0,0,0);
                    bD[j] = __builtin_amdgcn_mfma_f32_16x16x32_f16(w2h[j][kt], hbl, bD[j], 0,0,0);
                }
            }
#pragma unroll
            for (int j = 0; j < 2; ++j)
#pragma unroll
                for (int r = 0; r < 4; ++r)
                    kv[j][r] = bM[j][r] + LOINV*(bC[j][r] + bD[j][r]);
        };

        __syncthreads();                       // init: yf_0 + ts ready
#pragma unroll 1
        for (int s = 0; s < 49; ++s) {
            const float hstep = ts_l[s+1] - ts_l[s];
            const float h3 = hstep * (1.0f/3.0f);
            const float h8 = hstep * 0.125f;
            floatx4 k[2], pb[2];
            // ---- e = 0: k1 -> r1; p2 = y + h/3 k1 ----
            __syncthreads();                   // hf_e ready (A period done)
            b_mm(k);
#pragma unroll
            for (int j = 0; j < 2; ++j) { r1[j] = k[j]; pb[j] = yg[j] + h3*k[j]; }
            publish(pb);
            __syncthreads();                   // yf_{e+1} ready
            // ---- e = 1: U = k1+3k2; p3 = y + h k2 - h/3 k1; r1 = k1-k2 ----
            __syncthreads();
            b_mm(k);
#pragma unroll
            for (int j = 0; j < 2; ++j) {
                uu[j] = r1[j] + 3.0f*k[j];
                pb[j] = yg[j] + hstep*k[j] - h3*r1[j];
                r1[j] = r1[j] - k[j];
            }
            publish(pb);
            __syncthreads();
            // ---- e = 2: U += 3k3; p4 = y + h(D + k3) ----
            __syncthreads();
            b_mm(k);
#pragma unroll
            for (int j = 0; j < 2; ++j) {
                uu[j] = uu[j] + 3.0f*k[j];
                pb[j] = yg[j] + hstep*(r1[j] + k[j]);
            }
            publish(pb);
            __syncthreads();
            // ---- e = 3: y += h/8 (U + k4); store; p = y ----
            __syncthreads();
            b_mm(k);
#pragma unroll
            for (int j = 0; j < 2; ++j) yg[j] = yg[j] + h8*(uu[j] + k[j]);
            if (n16 < ROWS) {
                float* po = out + ((size_t)((blk*ROWS + n16)*50 + s + 1))*DIM + 32*wb + 4*quad;
                *(floatx4*)&po[0]  = yg[0];
                *(floatx4*)&po[16] = yg[1];
            }
            publish(yg);
            __syncthreads();
        }
    }
}

extern "C" void kernel_launch(void* const* d_in, const int* in_sizes, int n_in,
                              void* d_out, int out_size, void* d_ws, size_t ws_size,
                              hipStream_t stream) {
    const float* fp     = (const float*)d_in[0];
    const float* tsteps = (const float*)d_in[1];
    const float* W1     = (const float*)d_in[2];
    const float* b1     = (const float*)d_in[3];
    const float* W2     = (const float*)d_in[4];
    const float* b2     = (const float*)d_in[5];
    float* out          = (float*)d_out;

    ode_co_kernel<<<NBLK, 512, 0, stream>>>(fp, tsteps, W1, b1, W2, b2, out);
}